// Round 3
// baseline (223.863 us; speedup 1.0000x reference)
//
#include <hip/hip_runtime.h>

#define TL 124
#define CL 144
#define HL 36

typedef unsigned short u16;
typedef short bf16x8 __attribute__((ext_vector_type(8)));
typedef float f32x4  __attribute__((ext_vector_type(4)));

// LDS (bytes), 40960 total -> 4 blocks/CU (4 x 40960 = 160 KiB exactly):
//   k   @ 0     : bf16 [124][40]  = 9920   (cols 36..39 written as zeros)
//   gap @ 9920  : 16 B zeros (phase-S zero fragment for K-tail, hi>=1)
//   q   @ 9936  : bf16 [124][40]  = 9920   (ends 19856)
//   wei @ 0     : bf16 [124][128] = 31744  (overlays k/gap/q after scores barrier; XOR-swizzled)
//   vT  @ 31744 : bf16 [36][128]  = 9216   (vT[h][t], XOR-swizzled)
#define KQ_ST   40
#define GAP_B   9920
#define Q_B     9936
#define VT_B    31744
#define ZEROP_B 128     // wei row 0, cols 64..71: guaranteed masked-zero after softmax
#define LDS_BYTES 40960

// ws image: bf16 [5 kchunks][144 h_padded][40 kcols]; h_padded = 48*sec + hh,
// sec 0/1/2 = Wk/Wq/Wv, hh<36 valid else 0; kcol = 32*chunk + kk, kk<32 & kc<144 valid.
#define WS_ELEMS (5 * 144 * 40)

__device__ __forceinline__ u16 f2b(float f) {
    union { float f; unsigned u; } c; c.f = f;
    unsigned u = c.u;
    u += 0x7FFFu + ((u >> 16) & 1u);     // round-to-nearest-even
    return (u16)(u >> 16);
}

__global__ void prepack_w(const float* __restrict__ Wk, const float* __restrict__ Wq,
                          const float* __restrict__ Wv, u16* __restrict__ wt) {
    int i = blockIdx.x * 256 + threadIdx.x;
    if (i >= WS_ELEMS) return;
    int kk = i % 40;
    int hp = (i / 40) % 144;
    int ck = i / (40 * 144);
    int sec = hp / 48, hh = hp % 48;
    int kc = ck * 32 + kk;
    float v = 0.f;
    if (kk < 32 && kc < CL && hh < HL) {
        const float* W = (sec == 0) ? Wk : (sec == 1) ? Wq : Wv;
        v = W[kc * HL + hh];
    }
    wt[i] = f2b(v);
}

template<int USEWS>
__global__ __launch_bounds__(256, 4)
void head_mfma(const float* __restrict__ x,
               const float* __restrict__ Wk, const float* __restrict__ Wq,
               const float* __restrict__ Wv,
               const u16* __restrict__ wt,
               float* __restrict__ out)
{
    extern __shared__ char lds[];
    char* L = lds;

    const int tid = threadIdx.x;
    const int wv  = tid >> 6;          // wave 0..3
    const int l   = tid & 63;
    const int lo  = l & 15;
    const int hi  = l >> 4;
    const int b   = blockIdx.x;
    const float* xb = x + (size_t)b * (TL * CL);

    // prologue: zero the 16-B gap (read by phase-S K-tail fragments, hi>=1)
    if (tid < 2) *(uint2*)(L + GAP_B + tid * 8) = make_uint2(0u, 0u);

    const int mt0 = wv * 2;            // this wave's 2 M-tiles

    // ---------------- phase K: [k|q|v] = x @ [Wk|Wq|Wv] (MFMA), per-m to cap regs ----------------
    #pragma unroll
    for (int m = 0; m < 2; ++m) {
        int trow = 16 * (mt0 + m) + lo;
        if (trow > TL - 1) trow = TL - 1;          // clamped rows produce discarded outputs
        const float* px = xb + trow * CL;

        // batch all x loads for this m (10 dwordx4, one dependency chain)
        float4 xr[5][2];
        #pragma unroll
        for (int ks = 0; ks < 5; ++ks)
            if (ks < 4 || hi < 2) {                // cols 128..143 exist only for hi<2
                xr[ks][0] = *(const float4*)(px + ks * 32 + hi * 8);
                xr[ks][1] = *(const float4*)(px + ks * 32 + hi * 8 + 4);
            }
        bf16x8 ah[5];
        #pragma unroll
        for (int ks = 0; ks < 5; ++ks) {
            if (ks < 4 || hi < 2) {
                const float f[8] = {xr[ks][0].x, xr[ks][0].y, xr[ks][0].z, xr[ks][0].w,
                                    xr[ks][1].x, xr[ks][1].y, xr[ks][1].z, xr[ks][1].w};
                #pragma unroll
                for (int j = 0; j < 8; ++j) ah[ks][j] = (short)f2b(f[j]);
            } else {
                ah[ks] = (bf16x8){0,0,0,0,0,0,0,0};
            }
        }

        f32x4 acc[9];
        #pragma unroll
        for (int n = 0; n < 9; ++n) acc[n] = (f32x4){0.f, 0.f, 0.f, 0.f};

        #pragma unroll
        for (int ks = 0; ks < 5; ++ks) {
            bf16x8 bfr[9];
            #pragma unroll
            for (int nt = 0; nt < 9; ++nt) {
                if (USEWS) {
                    bfr[nt] = *(const bf16x8*)(wt + (size_t)(ks * 144 + 16 * nt + lo) * 40 + hi * 8);
                } else {
                    int hp = 16 * nt + lo;
                    int sec = hp / 48, hh = hp % 48;
                    const float* W = (sec == 0) ? Wk : (sec == 1) ? Wq : Wv;
                    if (hh < HL && (ks < 4 || hi < 2)) {
                        #pragma unroll
                        for (int j = 0; j < 8; ++j)
                            bfr[nt][j] = (short)f2b(W[(ks * 32 + hi * 8 + j) * HL + hh]);
                    } else bfr[nt] = (bf16x8){0,0,0,0,0,0,0,0};
                }
            }
            #pragma unroll
            for (int nt = 0; nt < 9; ++nt)
                acc[nt] = __builtin_amdgcn_mfma_f32_16x16x32_bf16(ah[ks], bfr[nt], acc[nt], 0, 0, 0);
        }

        // D-writes: k (nt 0..2), q (nt 3..5), vT (nt 6..8). D layout: row=hi*4+r, col=lo.
        const int tb = 16 * (mt0 + m) + hi * 4;
        #pragma unroll
        for (int nt = 0; nt < 9; ++nt) {
            if (nt < 6) {
                u16* dst = (u16*)(L + ((nt < 3) ? 0 : Q_B));
                const int h = 16 * (nt - ((nt < 3) ? 0 : 3)) + lo;
                if (h < KQ_ST) {                   // cols 36..39 get acc==0 (W zero-padded)
                    #pragma unroll
                    for (int r = 0; r < 4; ++r) {
                        const int t = tb + r;
                        if (t < TL) dst[t * KQ_ST + h] = f2b(acc[nt][r]);
                    }
                }
            } else {
                const int hv = 16 * (nt - 6) + lo;
                if (hv < HL) {
                    union { u16 s[4]; uint2 d; } pk;
                    #pragma unroll
                    for (int r = 0; r < 4; ++r) pk.s[r] = f2b(acc[nt][r]);
                    int byt = VT_B + hv * 256 + tb * 2;
                    byt ^= (hv & 7) << 4;
                    *(uint2*)(L + byt) = pk.d;     // cols >=124 hold finite garbage; wei=0 there
                }
            }
        }
    }
    __syncthreads();

    // ---------------- phase S: scores = k @ q^T (MFMA) ----------------
    f32x4 sa[2][8];
    #pragma unroll
    for (int m = 0; m < 2; ++m)
        #pragma unroll
        for (int n = 0; n < 8; ++n) sa[m][n] = (f32x4){0.f, 0.f, 0.f, 0.f};

    #pragma unroll
    for (int ks = 0; ks < 2; ++ks) {
        bf16x8 af[2];
        #pragma unroll
        for (int m = 0; m < 2; ++m) {
            const int row = 16 * (mt0 + m) + lo;   // rows >=124 read garbage -> discarded rows
            const int byt = (ks == 0) ? (row * 80 + hi * 16)
                                      : ((hi == 0) ? (row * 80 + 64) : GAP_B);
            af[m] = *(const bf16x8*)(L + byt);
        }
        #pragma unroll
        for (int nt = 0; nt < 8; ++nt) {
            const int row = 16 * nt + lo;          // rows >=124 read garbage -> masked cols
            const int byt = (ks == 0) ? (Q_B + row * 80 + hi * 16)
                                      : ((hi == 0) ? (Q_B + row * 80 + 64) : GAP_B);
            const bf16x8 bq = *(const bf16x8*)(L + byt);
            #pragma unroll
            for (int m = 0; m < 2; ++m)
                sa[m][nt] = __builtin_amdgcn_mfma_f32_16x16x32_bf16(af[m], bq, sa[m][nt], 0, 0, 0);
        }
    }
    __syncthreads();   // all k/q reads done before wei overlays them

    // ---------------- softmax (causal), write wei (bf16, swizzled) ----------------
    const float scl = 1.0f / 12.0f;    // C^-0.5, C = 144 (faithful to reference)
    #pragma unroll
    for (int m = 0; m < 2; ++m) {
        #pragma unroll
        for (int r = 0; r < 4; ++r) {
            const int t = 16 * (mt0 + m) + hi * 4 + r;
            if (t < TL) {                          // uniform per 16-lane group
                float v8[8];
                float mx = -__builtin_inff();
                #pragma unroll
                for (int nt = 0; nt < 8; ++nt) {
                    const float sc = sa[m][nt][r] * scl;
                    v8[nt] = (16 * nt + lo <= t) ? sc : -__builtin_inff();
                    mx = fmaxf(mx, v8[nt]);
                }
                mx = fmaxf(mx, __shfl_xor(mx, 1));
                mx = fmaxf(mx, __shfl_xor(mx, 2));
                mx = fmaxf(mx, __shfl_xor(mx, 4));
                mx = fmaxf(mx, __shfl_xor(mx, 8));
                float e8[8], sum = 0.f;
                #pragma unroll
                for (int nt = 0; nt < 8; ++nt) { e8[nt] = __expf(v8[nt] - mx); sum += e8[nt]; }
                sum += __shfl_xor(sum, 1);
                sum += __shfl_xor(sum, 2);
                sum += __shfl_xor(sum, 4);
                sum += __shfl_xor(sum, 8);
                const float rs = __builtin_amdgcn_rcpf(sum);
                #pragma unroll
                for (int nt = 0; nt < 8; ++nt) {
                    int byt = t * 256 + (16 * nt + lo) * 2;
                    byt ^= (t & 7) << 4;
                    *(u16*)(L + byt) = f2b(e8[nt] * rs);
                }
            }
        }
    }
    __syncthreads();

    // ---------------- phase P: out = wei @ v (MFMA), direct global store ----------------
    f32x4 pa[2][3];
    #pragma unroll
    for (int m = 0; m < 2; ++m)
        #pragma unroll
        for (int n = 0; n < 3; ++n) pa[m][n] = (f32x4){0.f, 0.f, 0.f, 0.f};

    #pragma unroll
    for (int ks = 0; ks < 4; ++ks) {
        bf16x8 aw[2];
        #pragma unroll
        for (int m = 0; m < 2; ++m) {
            int row = 16 * (mt0 + m) + lo;
            if (row > TL - 1) row = TL - 1;        // clamp: rows 124..127 discarded
            int byt = row * 256 + (ks * 32 + hi * 8) * 2;
            byt ^= (row & 7) << 4;
            aw[m] = *(const bf16x8*)(L + byt);
        }
        #pragma unroll
        for (int nt = 0; nt < 3; ++nt) {
            const int h = 16 * nt + lo;
            int byt;
            if (h < HL) {
                byt = VT_B + h * 256 + (ks * 32 + hi * 8) * 2;
                byt ^= (h & 7) << 4;
            } else {
                byt = ZEROP_B;                     // broadcast 16 B of masked-zero wei row 0
            }
            const bf16x8 bv = *(const bf16x8*)(L + byt);
            #pragma unroll
            for (int m = 0; m < 2; ++m)
                pa[m][nt] = __builtin_amdgcn_mfma_f32_16x16x32_bf16(aw[m], bv, pa[m][nt], 0, 0, 0);
        }
    }

    float* ob = out + (size_t)b * (TL * HL);
    #pragma unroll
    for (int m = 0; m < 2; ++m) {
        #pragma unroll
        for (int nt = 0; nt < 3; ++nt) {
            #pragma unroll
            for (int r = 0; r < 4; ++r) {
                const int t = 16 * (mt0 + m) + hi * 4 + r;
                const int h = 16 * nt + lo;
                if (t < TL && h < HL) ob[t * HL + h] = pa[m][nt][r];
            }
        }
    }
}

extern "C" void kernel_launch(void* const* d_in, const int* in_sizes, int n_in,
                              void* d_out, int out_size, void* d_ws, size_t ws_size,
                              hipStream_t stream) {
    const float* x  = (const float*)d_in[0];
    const float* Wk = (const float*)d_in[1];
    const float* Wq = (const float*)d_in[2];
    const float* Wv = (const float*)d_in[3];
    float* out = (float*)d_out;
    const int B = in_sizes[0] / (TL * CL);   // 4096

    if (ws_size >= (size_t)WS_ELEMS * sizeof(u16)) {
        prepack_w<<<(WS_ELEMS + 255) / 256, 256, 0, stream>>>(Wk, Wq, Wv, (u16*)d_ws);
        head_mfma<1><<<dim3(B), dim3(256), LDS_BYTES, stream>>>(x, Wk, Wq, Wv, (const u16*)d_ws, out);
    } else {
        head_mfma<0><<<dim3(B), dim3(256), LDS_BYTES, stream>>>(x, Wk, Wq, Wv, nullptr, out);
    }
}